// Round 1
// baseline (489.161 us; speedup 1.0000x reference)
//
#include <hip/hip_runtime.h>

#define MAXV 127.0f
#define Mdim 8192
#define Ndim 4096
#define Kdim 4096
#define BM 128
#define BN 128
#define BK 64

typedef __attribute__((ext_vector_type(4))) int int32x4;

__device__ __forceinline__ void async_load16(const void* g, void* l) {
  __builtin_amdgcn_global_load_lds(
      (const __attribute__((address_space(1))) unsigned int*)g,
      (__attribute__((address_space(3))) unsigned int*)l, 16, 0, 0);
}

__global__ void init_amax_kernel(int* p) {
  p[0] = 0;
  p[1] = 0;
}

__global__ void amax_abs_kernel(const float4* __restrict__ in, int n4,
                                int* __restrict__ out_bits) {
  float m = 0.0f;
  int stride = gridDim.x * blockDim.x;
  for (int i = blockIdx.x * blockDim.x + threadIdx.x; i < n4; i += stride) {
    float4 v = in[i];
    m = fmaxf(m, fmaxf(fmaxf(fabsf(v.x), fabsf(v.y)),
                       fmaxf(fabsf(v.z), fabsf(v.w))));
  }
  // wave-64 reduction
  for (int off = 32; off > 0; off >>= 1)
    m = fmaxf(m, __shfl_down(m, off));
  __shared__ float sm[4];
  if ((threadIdx.x & 63) == 0) sm[threadIdx.x >> 6] = m;
  __syncthreads();
  if (threadIdx.x == 0) {
    float mm = fmaxf(fmaxf(sm[0], sm[1]), fmaxf(sm[2], sm[3]));
    atomicMax(out_bits, __float_as_int(mm));  // values >= 0: int order == float order
  }
}

__global__ void quant_kernel(const float4* __restrict__ in, int n4,
                             const int* __restrict__ amax_bits,
                             char4* __restrict__ out) {
  float sc = MAXV / __int_as_float(*amax_bits);
  int stride = gridDim.x * blockDim.x;
  for (int i = blockIdx.x * blockDim.x + threadIdx.x; i < n4; i += stride) {
    float4 v = in[i];
    char4 q;
    q.x = (signed char)(int)fminf(fmaxf(rintf(v.x * sc), -MAXV), MAXV);
    q.y = (signed char)(int)fminf(fmaxf(rintf(v.y * sc), -MAXV), MAXV);
    q.z = (signed char)(int)fminf(fmaxf(rintf(v.z * sc), -MAXV), MAXV);
    q.w = (signed char)(int)fminf(fmaxf(rintf(v.w * sc), -MAXV), MAXV);
    out[i] = q;
  }
}

// C[m][n] = sum_k Aq[m][k] * Bq[n][k]  (both K-contiguous), dequant + bias.
// m97-style: 128x128 tile, BK=64 int8 (64 B LDS rows), global_load_lds x16,
// 4 waves in 2x2, each 64x64 via 4x4 grid of 16x16x64 i8 MFMA.
__global__ __launch_bounds__(256) void gemm_i8_kernel(
    const signed char* __restrict__ Aq, const signed char* __restrict__ Bq,
    const float* __restrict__ bias, const int* __restrict__ amax_bits,
    float* __restrict__ out) {
  __shared__ signed char As[BM * BK];  // row-major [128][64]
  __shared__ signed char Bs[BN * BK];

  const int tid = threadIdx.x;
  const int lane = tid & 63;
  const int w = tid >> 6;
  const int wm = w >> 1;  // wave row in 2x2
  const int wn = w & 1;   // wave col

  const int m0 = blockIdx.y * BM;
  const int n0 = blockIdx.x * BN;

  int32x4 acc[4][4] = {};

  // Staging: chunk c = r*256 + tid covers row c>>2 (of 128), 16B-chunk c&3.
  // LDS dst = base(r*4096 + w*1024) + lane*16 == As[row*64 + (c&3)*16]. Exact
  // match for the wave-uniform-base + lane*16 scatter of global_load_lds.
  const signed char* Abase =
      Aq + (size_t)(m0 + (tid >> 2)) * Kdim + (tid & 3) * 16;
  const signed char* Bbase =
      Bq + (size_t)(n0 + (tid >> 2)) * Kdim + (tid & 3) * 16;
  const size_t rowskip = (size_t)64 * Kdim;  // second staging round: +64 rows

  const int aoff = (wm * 64 + (lane & 15)) * BK + (lane >> 4) * 16;
  const int boff = (wn * 64 + (lane & 15)) * BK + (lane >> 4) * 16;

  for (int k0 = 0; k0 < Kdim; k0 += BK) {
    async_load16(Abase + k0, &As[w * 1024]);
    async_load16(Abase + rowskip + k0, &As[4096 + w * 1024]);
    async_load16(Bbase + k0, &Bs[w * 1024]);
    async_load16(Bbase + rowskip + k0, &Bs[4096 + w * 1024]);
    __syncthreads();

    int32x4 a[4], b[4];
#pragma unroll
    for (int i = 0; i < 4; i++)
      a[i] = *(const int32x4*)&As[aoff + i * 16 * BK];
#pragma unroll
    for (int j = 0; j < 4; j++)
      b[j] = *(const int32x4*)&Bs[boff + j * 16 * BK];

#pragma unroll
    for (int i = 0; i < 4; i++)
#pragma unroll
      for (int j = 0; j < 4; j++)
        acc[i][j] =
            __builtin_amdgcn_mfma_i32_16x16x64_i8(a[i], b[j], acc[i][j], 0, 0, 0);
    __syncthreads();
  }

  // Dequant + bias epilogue. C/D: col = lane&15, row = (lane>>4)*4 + reg.
  const float sx = MAXV / __int_as_float(amax_bits[0]);
  const float sw = MAXV / __int_as_float(amax_bits[1]);
  const float inv = 1.0f / (sx * sw);
  const int crow = (lane >> 4) * 4;
  const int ccol = lane & 15;
#pragma unroll
  for (int j = 0; j < 4; j++) {
    const int n = n0 + wn * 64 + j * 16 + ccol;
    const float bv = bias[n];
#pragma unroll
    for (int i = 0; i < 4; i++) {
      const int m = m0 + wm * 64 + i * 16 + crow;
      float* op = out + (size_t)m * Ndim + n;
#pragma unroll
      for (int r = 0; r < 4; r++)
        op[(size_t)r * Ndim] = (float)acc[i][j][r] * inv + bv;
    }
  }
}

extern "C" void kernel_launch(void* const* d_in, const int* in_sizes, int n_in,
                              void* d_out, int out_size, void* d_ws,
                              size_t ws_size, hipStream_t stream) {
  const float* x = (const float*)d_in[0];
  const float* wgt = (const float*)d_in[1];
  const float* bias = (const float*)d_in[2];
  float* out = (float*)d_out;

  int* amax = (int*)d_ws;
  signed char* qx = (signed char*)d_ws + 256;
  signed char* qw = qx + (size_t)Mdim * Kdim;

  const int nx4 = (Mdim * Kdim) / 4;  // 8388608
  const int nw4 = (Ndim * Kdim) / 4;  // 4194304

  hipLaunchKernelGGL(init_amax_kernel, dim3(1), dim3(1), 0, stream, amax);
  hipLaunchKernelGGL(amax_abs_kernel, dim3(2048), dim3(256), 0, stream,
                     (const float4*)x, nx4, amax);
  hipLaunchKernelGGL(amax_abs_kernel, dim3(2048), dim3(256), 0, stream,
                     (const float4*)wgt, nw4, amax + 1);
  hipLaunchKernelGGL(quant_kernel, dim3(2048), dim3(256), 0, stream,
                     (const float4*)x, nx4, amax, (char4*)qx);
  hipLaunchKernelGGL(quant_kernel, dim3(2048), dim3(256), 0, stream,
                     (const float4*)wgt, nw4, amax + 1, (char4*)qw);
  hipLaunchKernelGGL(gemm_i8_kernel, dim3(Ndim / BN, Mdim / BM), dim3(256), 0,
                     stream, qx, qw, bias, amax, out);
}

// Round 2
// 475.545 us; speedup vs baseline: 1.0286x; 1.0286x over previous
//
#include <hip/hip_runtime.h>

#define MAXV 127.0f
#define Mdim 8192
#define Ndim 4096
#define Kdim 4096
#define BM 128
#define BN 128
#define BK 64

// Elementwise-kernel geometry (sizes divide exactly; no tail handling)
#define EW_GRID 2048
#define EW_BLOCK 256
#define EW_STRIDE (EW_GRID * EW_BLOCK)      // 524288 threads
#define NX4 (Mdim * Kdim / 4)               // 8388608 float4 in x  (16 per thread)
#define NW4 (Ndim * Kdim / 4)               // 4194304 float4 in w  (8 per thread)

typedef __attribute__((ext_vector_type(4))) int int32x4;

__device__ __forceinline__ void async_load16(const void* g, void* l) {
  __builtin_amdgcn_global_load_lds(
      (const __attribute__((address_space(1))) unsigned int*)g,
      (__attribute__((address_space(3))) unsigned int*)l, 16, 0, 0);
}

__device__ __forceinline__ float amax4(float4 v) {
  return fmaxf(fmaxf(fabsf(v.x), fabsf(v.y)), fmaxf(fabsf(v.z), fabsf(v.w)));
}

// One pass over BOTH tensors; per-thread maxima, wave shfl-reduce, one atomic
// per tensor per block. 4 independent float4 loads in flight per iteration.
__global__ __launch_bounds__(EW_BLOCK) void amax_both_kernel(
    const float4* __restrict__ x, const float4* __restrict__ w,
    int* __restrict__ out_bits) {
  const int t = blockIdx.x * EW_BLOCK + threadIdx.x;
  float mx = 0.0f, mw = 0.0f;
#pragma unroll
  for (int i = 0; i < 4; i++) {  // 16 iters over x as 4 rounds of 4
    float4 a = x[t + (4 * i + 0) * EW_STRIDE];
    float4 b = x[t + (4 * i + 1) * EW_STRIDE];
    float4 c = x[t + (4 * i + 2) * EW_STRIDE];
    float4 d = x[t + (4 * i + 3) * EW_STRIDE];
    mx = fmaxf(mx, fmaxf(fmaxf(amax4(a), amax4(b)), fmaxf(amax4(c), amax4(d))));
  }
#pragma unroll
  for (int i = 0; i < 2; i++) {  // 8 iters over w as 2 rounds of 4
    float4 a = w[t + (4 * i + 0) * EW_STRIDE];
    float4 b = w[t + (4 * i + 1) * EW_STRIDE];
    float4 c = w[t + (4 * i + 2) * EW_STRIDE];
    float4 d = w[t + (4 * i + 3) * EW_STRIDE];
    mw = fmaxf(mw, fmaxf(fmaxf(amax4(a), amax4(b)), fmaxf(amax4(c), amax4(d))));
  }
  for (int off = 32; off > 0; off >>= 1) {
    mx = fmaxf(mx, __shfl_down(mx, off));
    mw = fmaxf(mw, __shfl_down(mw, off));
  }
  __shared__ float sm[8];
  if ((threadIdx.x & 63) == 0) {
    sm[threadIdx.x >> 6] = mx;
    sm[4 + (threadIdx.x >> 6)] = mw;
  }
  __syncthreads();
  if (threadIdx.x == 0) {
    atomicMax(out_bits,
              __float_as_int(fmaxf(fmaxf(sm[0], sm[1]), fmaxf(sm[2], sm[3]))));
    atomicMax(out_bits + 1,
              __float_as_int(fmaxf(fmaxf(sm[4], sm[5]), fmaxf(sm[6], sm[7]))));
  }
}

__device__ __forceinline__ char4 quant4(float4 v, float s) {
  char4 q;
  q.x = (signed char)(int)fminf(fmaxf(rintf(v.x * s), -MAXV), MAXV);
  q.y = (signed char)(int)fminf(fmaxf(rintf(v.y * s), -MAXV), MAXV);
  q.z = (signed char)(int)fminf(fmaxf(rintf(v.z * s), -MAXV), MAXV);
  q.w = (signed char)(int)fminf(fmaxf(rintf(v.w * s), -MAXV), MAXV);
  return q;
}

// Quantize BOTH tensors in one kernel (reads should be LLC-warm after amax).
__global__ __launch_bounds__(EW_BLOCK) void quant_both_kernel(
    const float4* __restrict__ x, const float4* __restrict__ w,
    const int* __restrict__ amax_bits, char4* __restrict__ qx,
    char4* __restrict__ qw) {
  const float sx = MAXV / __int_as_float(amax_bits[0]);
  const float sw = MAXV / __int_as_float(amax_bits[1]);
  const int t = blockIdx.x * EW_BLOCK + threadIdx.x;
#pragma unroll
  for (int i = 0; i < 4; i++) {
    int i0 = t + (4 * i + 0) * EW_STRIDE, i1 = t + (4 * i + 1) * EW_STRIDE;
    int i2 = t + (4 * i + 2) * EW_STRIDE, i3 = t + (4 * i + 3) * EW_STRIDE;
    float4 a = x[i0], b = x[i1], c = x[i2], d = x[i3];
    qx[i0] = quant4(a, sx);
    qx[i1] = quant4(b, sx);
    qx[i2] = quant4(c, sx);
    qx[i3] = quant4(d, sx);
  }
#pragma unroll
  for (int i = 0; i < 2; i++) {
    int i0 = t + (4 * i + 0) * EW_STRIDE, i1 = t + (4 * i + 1) * EW_STRIDE;
    int i2 = t + (4 * i + 2) * EW_STRIDE, i3 = t + (4 * i + 3) * EW_STRIDE;
    float4 a = w[i0], b = w[i1], c = w[i2], d = w[i3];
    qw[i0] = quant4(a, sw);
    qw[i1] = quant4(b, sw);
    qw[i2] = quant4(c, sw);
    qw[i3] = quant4(d, sw);
  }
}

// C[m][n] = sum_k Aq[m][k] * Bq[n][k]  (both K-contiguous), dequant + bias.
// m97-style: 128x128 tile, BK=64 int8 (64 B LDS rows), global_load_lds x16,
// 4 waves in 2x2, each 64x64 via 4x4 grid of 16x16x64 i8 MFMA.
// Known plateau: ~36% of i8 ceiling (barrier-drain bound) — unchanged this round.
__global__ __launch_bounds__(256) void gemm_i8_kernel(
    const signed char* __restrict__ Aq, const signed char* __restrict__ Bq,
    const float* __restrict__ bias, const int* __restrict__ amax_bits,
    float* __restrict__ out) {
  __shared__ signed char As[BM * BK];  // row-major [128][64]
  __shared__ signed char Bs[BN * BK];

  const int tid = threadIdx.x;
  const int lane = tid & 63;
  const int w = tid >> 6;
  const int wm = w >> 1;  // wave row in 2x2
  const int wn = w & 1;   // wave col

  const int m0 = blockIdx.y * BM;
  const int n0 = blockIdx.x * BN;

  int32x4 acc[4][4] = {};

  const signed char* Abase =
      Aq + (size_t)(m0 + (tid >> 2)) * Kdim + (tid & 3) * 16;
  const signed char* Bbase =
      Bq + (size_t)(n0 + (tid >> 2)) * Kdim + (tid & 3) * 16;
  const size_t rowskip = (size_t)64 * Kdim;

  const int aoff = (wm * 64 + (lane & 15)) * BK + (lane >> 4) * 16;
  const int boff = (wn * 64 + (lane & 15)) * BK + (lane >> 4) * 16;

  for (int k0 = 0; k0 < Kdim; k0 += BK) {
    async_load16(Abase + k0, &As[w * 1024]);
    async_load16(Abase + rowskip + k0, &As[4096 + w * 1024]);
    async_load16(Bbase + k0, &Bs[w * 1024]);
    async_load16(Bbase + rowskip + k0, &Bs[4096 + w * 1024]);
    __syncthreads();

    int32x4 a[4], b[4];
#pragma unroll
    for (int i = 0; i < 4; i++)
      a[i] = *(const int32x4*)&As[aoff + i * 16 * BK];
#pragma unroll
    for (int j = 0; j < 4; j++)
      b[j] = *(const int32x4*)&Bs[boff + j * 16 * BK];

#pragma unroll
    for (int i = 0; i < 4; i++)
#pragma unroll
      for (int j = 0; j < 4; j++)
        acc[i][j] =
            __builtin_amdgcn_mfma_i32_16x16x64_i8(a[i], b[j], acc[i][j], 0, 0, 0);
    __syncthreads();
  }

  const float sx = MAXV / __int_as_float(amax_bits[0]);
  const float sw = MAXV / __int_as_float(amax_bits[1]);
  const float inv = 1.0f / (sx * sw);
  const int crow = (lane >> 4) * 4;
  const int ccol = lane & 15;
#pragma unroll
  for (int j = 0; j < 4; j++) {
    const int n = n0 + wn * 64 + j * 16 + ccol;
    const float bv = bias[n];
#pragma unroll
    for (int i = 0; i < 4; i++) {
      const int m = m0 + wm * 64 + i * 16 + crow;
      float* op = out + (size_t)m * Ndim + n;
#pragma unroll
      for (int r = 0; r < 4; r++)
        op[(size_t)r * Ndim] = (float)acc[i][j][r] * inv + bv;
    }
  }
}

extern "C" void kernel_launch(void* const* d_in, const int* in_sizes, int n_in,
                              void* d_out, int out_size, void* d_ws,
                              size_t ws_size, hipStream_t stream) {
  const float* x = (const float*)d_in[0];
  const float* wgt = (const float*)d_in[1];
  const float* bias = (const float*)d_in[2];
  float* out = (float*)d_out;

  int* amax = (int*)d_ws;
  signed char* qx = (signed char*)d_ws + 256;
  signed char* qw = qx + (size_t)Mdim * Kdim;

  hipMemsetAsync(amax, 0, 2 * sizeof(int), stream);
  hipLaunchKernelGGL(amax_both_kernel, dim3(EW_GRID), dim3(EW_BLOCK), 0, stream,
                     (const float4*)x, (const float4*)wgt, amax);
  hipLaunchKernelGGL(quant_both_kernel, dim3(EW_GRID), dim3(EW_BLOCK), 0,
                     stream, (const float4*)x, (const float4*)wgt, amax,
                     (char4*)qx, (char4*)qw);
  hipLaunchKernelGGL(gemm_i8_kernel, dim3(Ndim / BN, Mdim / BM), dim3(256), 0,
                     stream, qx, qw, bias, amax, out);
}